// Round 2
// baseline (270.676 us; speedup 1.0000x reference)
//
#include <hip/hip_runtime.h>

#define LL 16
#define CC 32
#define HIDN 16
#define HH 64
#define WW 64
#define HW 4096  // 64*64

// ws layout (floats): cum[L*2*HW] | U[L*HIDN*HW] | V[L*HIDN*HW]  (~8.9 MB)
#define CUM_OFF 0
#define U_OFF   (LL * 2 * HW)
#define V_OFF   (U_OFF + LL * HIDN * HW)

// ---------------- cumsum of flows over L ----------------
__global__ __launch_bounds__(256) void cumsum_kernel(const float* __restrict__ flows,
                                                     float* __restrict__ cum) {
    int idx = blockIdx.x * 256 + threadIdx.x;   // p*HW + pix, 0..2*HW-1
    float acc = 0.0f;
#pragma unroll
    for (int l = 0; l < LL; ++l) {
        acc += flows[l * 2 * HW + idx];
        cum[l * 2 * HW + idx] = acc;
    }
}

// ---------------- per-frame MLP halves ----------------
// U[l][o][px] = sum_c w1[o][c]    * img[l][c][px]
// V[l][o][px] = sum_c w1[o][32+c] * img[l][c][px] + b1[o]
__global__ __launch_bounds__(256) void uv_kernel(const float* __restrict__ images,
                                                 const float* __restrict__ w1,
                                                 const float* __restrict__ b1,
                                                 float* __restrict__ U,
                                                 float* __restrict__ V) {
    __shared__ float w1s[HIDN * 2 * CC];  // 1024 floats
    const int tid = threadIdx.x;
    ((float4*)w1s)[tid] = ((const float4*)w1)[tid];
    __syncthreads();

    const int l  = blockIdx.y;
    const int px = blockIdx.x * 256 + tid;
    const float* img = images + (size_t)l * CC * HW;

    float u[HIDN], v[HIDN];
#pragma unroll
    for (int o = 0; o < HIDN; ++o) { u[o] = 0.0f; v[o] = b1[o]; }

#pragma unroll 8
    for (int c = 0; c < CC; ++c) {
        float x = img[c * HW + px];
#pragma unroll
        for (int o = 0; o < HIDN; ++o) {
            u[o] = fmaf(w1s[o * 64 + c],      x, u[o]);
            v[o] = fmaf(w1s[o * 64 + CC + c], x, v[o]);
        }
    }
#pragma unroll
    for (int o = 0; o < HIDN; ++o) {
        U[(l * HIDN + o) * HW + px] = u[o];
        V[(l * HIDN + o) * HW + px] = v[o];
    }
}

// ---------------- main fused kernel (no atomics) ----------------
// grid: 1024 blocks; bid = tile*16 + t (t interleaved for load balance)
// block: 256 threads = 64 pixels (one image row) x 4 channel-groups of 8
__global__ __launch_bounds__(256) void gsp_main(const float* __restrict__ images,
                                                const float* __restrict__ ws,
                                                const float* __restrict__ w2,
                                                const float* __restrict__ b2,
                                                const float* __restrict__ decay_log,
                                                float* __restrict__ out) {
    __shared__ float w2s[2 * HIDN];
    __shared__ float b2s[2];
    const int tid = threadIdx.x;
    if (tid < 2 * HIDN) w2s[tid] = w2[tid];
    if (tid < 2)        b2s[tid] = b2[tid];
    __syncthreads();

    const int bid  = blockIdx.x;        // 0..1023
    const int t    = bid & 15;
    const int tile = bid >> 4;          // image row 0..63
    const int lane = tid & 63;          // x coordinate
    const int cg   = tid >> 6;          // channel group 0..3
    const int c0   = cg * 8;
    const int px   = tile * 64 + lane;

    const float* cum = ws + CUM_OFF;
    const float* U   = ws + U_OFF;
    const float* V   = ws + V_OFF;

    float ut[HIDN];
#pragma unroll
    for (int o = 0; o < HIDN; ++o) ut[o] = U[(t * HIDN + o) * HW + px];

    const float cumtx = cum[(t * 2)     * HW + px];
    const float cumty = cum[(t * 2 + 1) * HW + px];
    const float lam   = expf(decay_log[0]);

    // base grid: (2*i+1)/64 - 1
    const float bgx = (float)(2 * lane + 1) * (1.0f / 64.0f) - 1.0f;
    const float bgy = (float)(2 * tile + 1) * (1.0f / 64.0f) - 1.0f;

    float acc[8];
#pragma unroll
    for (int j = 0; j < 8; ++j) acc[j] = 0.0f;

    for (int k = 0; k <= t; ++k) {
        // tiny MLP: res = W2 * relu(U[t] + V[k]) + b2
        float res0 = b2s[0], res1 = b2s[1];
#pragma unroll
        for (int o = 0; o < HIDN; ++o) {
            float h = fmaxf(ut[o] + V[(k * HIDN + o) * HW + px], 0.0f);
            res0 = fmaf(w2s[o],        h, res0);
            res1 = fmaf(w2s[HIDN + o], h, res1);
        }

        float gx = bgx + cumtx - cum[(k * 2)     * HW + px] + res0;
        float gy = bgy + cumty - cum[(k * 2 + 1) * HW + px] + res1;

        // wrap x: mod(gx+1, 2) - 1  (floor-mod)
        float xp = gx + 1.0f;
        xp = xp - floorf(xp * 0.5f) * 2.0f;
        float gxw = xp - 1.0f;

        float ix = ((gxw + 1.0f) * 64.0f - 1.0f) * 0.5f;
        float iy = ((gy  + 1.0f) * 64.0f - 1.0f) * 0.5f;

        float ix0f = floorf(ix), iy0f = floorf(iy);
        float fx1 = ix - ix0f, fy1 = iy - iy0f;
        float fx0 = 1.0f - fx1, fy0 = 1.0f - fy1;
        int ix0 = (int)ix0f, iy0 = (int)iy0f;
        int ix1 = ix0 + 1,   iy1 = iy0 + 1;

        int   off[4];
        float cwt[4];
        {
            int xi[4] = {ix0, ix1, ix0, ix1};
            int yi[4] = {iy0, iy0, iy1, iy1};
            float wwv[4] = {fx0 * fy0, fx1 * fy0, fx0 * fy1, fx1 * fy1};
#pragma unroll
            for (int j = 0; j < 4; ++j) {
                bool valid = (xi[j] >= 0) & (xi[j] < WW) & (yi[j] >= 0) & (yi[j] < HH);
                int xc = min(max(xi[j], 0), WW - 1);
                int yc = min(max(yi[j], 0), HH - 1);
                off[j] = yc * WW + xc;
                cwt[j] = valid ? wwv[j] : 0.0f;
            }
        }

        const float wt = expf(-lam * (float)(t - k));
        const float w0 = cwt[0] * wt, w1v = cwt[1] * wt;
        const float w2v = cwt[2] * wt, w3v = cwt[3] * wt;

        const float* pk = images + ((size_t)k * CC + c0) * HW;
#pragma unroll
        for (int j = 0; j < 8; ++j) {
            const float* pl = pk + j * HW;
            float s = w0 * pl[off[0]] + w1v * pl[off[1]] + w2v * pl[off[2]] + w3v * pl[off[3]];
            acc[j] += s;
        }
    }

    float* po = out + ((size_t)t * CC + c0) * HW + px;
#pragma unroll
    for (int j = 0; j < 8; ++j) po[j * HW] = acc[j];
}

extern "C" void kernel_launch(void* const* d_in, const int* in_sizes, int n_in,
                              void* d_out, int out_size, void* d_ws, size_t ws_size,
                              hipStream_t stream) {
    const float* flows     = (const float*)d_in[0];  // (1,16,2,64,64)
    const float* images    = (const float*)d_in[1];  // (1,16,32,64,64)
    const float* decay_log = (const float*)d_in[2];  // scalar
    const float* w1        = (const float*)d_in[3];  // (16,64)
    const float* b1        = (const float*)d_in[4];  // (16,)
    const float* w2        = (const float*)d_in[5];  // (2,16)
    const float* b2        = (const float*)d_in[6];  // (2,)
    float* out = (float*)d_out;                      // (1,16,32,64,64)
    float* ws  = (float*)d_ws;

    // cumsum of flows over L
    cumsum_kernel<<<dim3(2 * HW / 256), dim3(256), 0, stream>>>(flows, ws + CUM_OFF);

    // per-frame MLP halves U, V
    uv_kernel<<<dim3(HW / 256, LL), dim3(256), 0, stream>>>(
        images, w1, b1, ws + U_OFF, ws + V_OFF);

    // main fused kernel (writes every output exactly once)
    gsp_main<<<dim3(64 * 16), dim3(256), 0, stream>>>(
        images, ws, w2, b2, decay_log, out);
}

// Round 3
// 156.672 us; speedup vs baseline: 1.7277x; 1.7277x over previous
//
#include <hip/hip_runtime.h>

#define LL 16
#define CC 32
#define HIDN 16
#define HH 64
#define WW 64
#define HW 4096  // 64*64

// ws layout (floats):
#define CUM_OFF  0                                  // L*2*HW      = 131072
#define U_OFF    (LL * 2 * HW)                      // L*HW*HIDN   = 1048576
#define V_OFF    (U_OFF + LL * HW * HIDN)           // L*HW*HIDN   = 1048576
#define IMGT_OFF (V_OFF + LL * HW * HIDN)           // L*HW*CC     = 2097152
// total = 4,325,376 floats (~16.5 MB)

// ---------------- cumsum of flows over L ----------------
__global__ __launch_bounds__(256) void cumsum_kernel(const float* __restrict__ flows,
                                                     float* __restrict__ cum) {
    int idx = blockIdx.x * 256 + threadIdx.x;   // p*HW + pix
    float acc = 0.0f;
#pragma unroll
    for (int l = 0; l < LL; ++l) {
        acc += flows[l * 2 * HW + idx];
        cum[l * 2 * HW + idx] = acc;
    }
}

// ---------------- prep: U/V halves (channel-last) + channel-last image copy ----
// U[l][px][o] = sum_c w1[o][c]    * img[l][c][px]
// V[l][px][o] = sum_c w1[o][32+c] * img[l][c][px] + b1[o]
// imgT[l][px][c] = img[l][c][px]
__global__ __launch_bounds__(256) void prep_kernel(const float* __restrict__ images,
                                                   const float* __restrict__ w1,
                                                   const float* __restrict__ b1,
                                                   float* __restrict__ ws) {
    __shared__ float w1s[HIDN * 2 * CC];  // 1024 floats
    const int tid = threadIdx.x;
    ((float4*)w1s)[tid] = ((const float4*)w1)[tid];
    __syncthreads();

    const int l  = blockIdx.y;
    const int px = blockIdx.x * 256 + tid;
    const float* img = images + (size_t)l * CC * HW;

    float x[CC];
#pragma unroll
    for (int c = 0; c < CC; ++c) x[c] = img[c * HW + px];

    float u[HIDN], v[HIDN];
#pragma unroll
    for (int o = 0; o < HIDN; ++o) { u[o] = 0.0f; v[o] = b1[o]; }
#pragma unroll
    for (int c = 0; c < CC; ++c) {
#pragma unroll
        for (int o = 0; o < HIDN; ++o) {
            u[o] = fmaf(w1s[o * 64 + c],      x[c], u[o]);
            v[o] = fmaf(w1s[o * 64 + CC + c], x[c], v[o]);
        }
    }

    float* Up = ws + U_OFF    + ((size_t)l * HW + px) * HIDN;
    float* Vp = ws + V_OFF    + ((size_t)l * HW + px) * HIDN;
    float* Tp = ws + IMGT_OFF + ((size_t)l * HW + px) * CC;
#pragma unroll
    for (int q = 0; q < 4; ++q) ((float4*)Up)[q] = ((float4*)u)[q];
#pragma unroll
    for (int q = 0; q < 4; ++q) ((float4*)Vp)[q] = ((float4*)v)[q];
#pragma unroll
    for (int q = 0; q < 8; ++q) ((float4*)Tp)[q] = ((float4*)x)[q];
}

// ---------------- main fused kernel ----------------
// grid: 1024 blocks, bid = t*64 + row   (balances t across CUs)
// block: 512 threads = 64 px  x  4 k-slices (ks)  x  2 channel halves (cg of 16)
__global__ __launch_bounds__(512, 4) void gsp_main(const float* __restrict__ ws,
                                                   const float* __restrict__ w2,
                                                   const float* __restrict__ b2,
                                                   const float* __restrict__ decay_log,
                                                   float* __restrict__ out) {
    __shared__ float w2s[2 * HIDN];
    __shared__ float b2s2[2];
    __shared__ float red[4][64][CC + 1];   // +1 pad -> conflict-free (33,792 B)

    const int tid = threadIdx.x;
    if (tid < 2 * HIDN) w2s[tid] = w2[tid];
    if (tid < 2)        b2s2[tid] = b2[tid];
    __syncthreads();

    const int bid = blockIdx.x;
    const int t   = bid >> 6;
    const int row = bid & 63;
    const int lpx = tid & 63;
    const int ks  = (tid >> 6) & 3;
    const int cg  = tid >> 8;           // 0..1
    const int c0  = cg * 16;
    const int px  = row * 64 + lpx;

    const float* cum = ws + CUM_OFF;
    const float* Ub  = ws + U_OFF;
    const float* Vb  = ws + V_OFF;
    const float* imT = ws + IMGT_OFF;

    float ut[HIDN];
    {
        const float4* up = (const float4*)(Ub + ((size_t)t * HW + px) * HIDN);
#pragma unroll
        for (int q = 0; q < 4; ++q) ((float4*)ut)[q] = up[q];
    }

    const float cumtx = cum[(t * 2)     * HW + px];
    const float cumty = cum[(t * 2 + 1) * HW + px];
    const float lam   = expf(decay_log[0]);
    const float bgx   = (float)(2 * lpx + 1) * (1.0f / 64.0f) - 1.0f;
    const float bgy   = (float)(2 * row + 1) * (1.0f / 64.0f) - 1.0f;

    float acc[16];
#pragma unroll
    for (int j = 0; j < 16; ++j) acc[j] = 0.0f;

    for (int k = ks; k <= t; k += 4) {
        // tiny MLP: res = W2 * relu(U[t] + V[k]) + b2
        float res0 = b2s2[0], res1 = b2s2[1];
        {
            const float4* vp = (const float4*)(Vb + ((size_t)k * HW + px) * HIDN);
#pragma unroll
            for (int q = 0; q < 4; ++q) {
                float4 vq = vp[q];
                float h0 = fmaxf(ut[q * 4 + 0] + vq.x, 0.0f);
                float h1 = fmaxf(ut[q * 4 + 1] + vq.y, 0.0f);
                float h2 = fmaxf(ut[q * 4 + 2] + vq.z, 0.0f);
                float h3 = fmaxf(ut[q * 4 + 3] + vq.w, 0.0f);
                res0 = fmaf(w2s[q * 4 + 0], h0, res0);
                res0 = fmaf(w2s[q * 4 + 1], h1, res0);
                res0 = fmaf(w2s[q * 4 + 2], h2, res0);
                res0 = fmaf(w2s[q * 4 + 3], h3, res0);
                res1 = fmaf(w2s[HIDN + q * 4 + 0], h0, res1);
                res1 = fmaf(w2s[HIDN + q * 4 + 1], h1, res1);
                res1 = fmaf(w2s[HIDN + q * 4 + 2], h2, res1);
                res1 = fmaf(w2s[HIDN + q * 4 + 3], h3, res1);
            }
        }

        float gx = bgx + cumtx - cum[(k * 2)     * HW + px] + res0;
        float gy = bgy + cumty - cum[(k * 2 + 1) * HW + px] + res1;

        // wrap x: mod(gx+1, 2) - 1  (floor-mod)
        float xp = gx + 1.0f;
        xp = xp - floorf(xp * 0.5f) * 2.0f;
        float gxw = xp - 1.0f;

        float ix = ((gxw + 1.0f) * 64.0f - 1.0f) * 0.5f;
        float iy = ((gy  + 1.0f) * 64.0f - 1.0f) * 0.5f;

        float ix0f = floorf(ix), iy0f = floorf(iy);
        float fx1 = ix - ix0f, fy1 = iy - iy0f;
        float fx0 = 1.0f - fx1, fy0 = 1.0f - fy1;
        int ix0 = (int)ix0f, iy0 = (int)iy0f;
        int ix1 = ix0 + 1,   iy1 = iy0 + 1;

        int   off[4];
        float cwt[4];
        {
            int xi[4] = {ix0, ix1, ix0, ix1};
            int yi[4] = {iy0, iy0, iy1, iy1};
            float wwv[4] = {fx0 * fy0, fx1 * fy0, fx0 * fy1, fx1 * fy1};
#pragma unroll
            for (int j = 0; j < 4; ++j) {
                bool valid = (xi[j] >= 0) & (xi[j] < WW) & (yi[j] >= 0) & (yi[j] < HH);
                int xc = min(max(xi[j], 0), WW - 1);
                int yc = min(max(yi[j], 0), HH - 1);
                off[j] = yc * WW + xc;
                cwt[j] = valid ? wwv[j] : 0.0f;
            }
        }

        const float wt = expf(-lam * (float)(t - k));
        const float* kbase = imT + (size_t)k * HW * CC + c0;
#pragma unroll
        for (int j = 0; j < 4; ++j) {
            const float wj = cwt[j] * wt;
            const float4* cp = (const float4*)(kbase + (size_t)off[j] * CC);
            float4 p0 = cp[0], p1 = cp[1], p2 = cp[2], p3 = cp[3];
            acc[0]  = fmaf(wj, p0.x, acc[0]);  acc[1]  = fmaf(wj, p0.y, acc[1]);
            acc[2]  = fmaf(wj, p0.z, acc[2]);  acc[3]  = fmaf(wj, p0.w, acc[3]);
            acc[4]  = fmaf(wj, p1.x, acc[4]);  acc[5]  = fmaf(wj, p1.y, acc[5]);
            acc[6]  = fmaf(wj, p1.z, acc[6]);  acc[7]  = fmaf(wj, p1.w, acc[7]);
            acc[8]  = fmaf(wj, p2.x, acc[8]);  acc[9]  = fmaf(wj, p2.y, acc[9]);
            acc[10] = fmaf(wj, p2.z, acc[10]); acc[11] = fmaf(wj, p2.w, acc[11]);
            acc[12] = fmaf(wj, p3.x, acc[12]); acc[13] = fmaf(wj, p3.y, acc[13]);
            acc[14] = fmaf(wj, p3.z, acc[14]); acc[15] = fmaf(wj, p3.w, acc[15]);
        }
    }

    // LDS 4-way reduce across k-slices
#pragma unroll
    for (int j = 0; j < 16; ++j) red[ks][lpx][c0 + j] = acc[j];
    __syncthreads();

    // 512 threads cover 64px x 32ch outputs, 4 channels each
    const int opx = tid & 63;
    const int oc0 = (tid >> 6) * 4;          // 0..28
    const int gpx = row * 64 + opx;
#pragma unroll
    for (int q = 0; q < 4; ++q) {
        float s = red[0][opx][oc0 + q] + red[1][opx][oc0 + q]
                + red[2][opx][oc0 + q] + red[3][opx][oc0 + q];
        out[((size_t)t * CC + oc0 + q) * HW + gpx] = s;
    }
}

extern "C" void kernel_launch(void* const* d_in, const int* in_sizes, int n_in,
                              void* d_out, int out_size, void* d_ws, size_t ws_size,
                              hipStream_t stream) {
    const float* flows     = (const float*)d_in[0];
    const float* images    = (const float*)d_in[1];
    const float* decay_log = (const float*)d_in[2];
    const float* w1        = (const float*)d_in[3];
    const float* b1        = (const float*)d_in[4];
    const float* w2        = (const float*)d_in[5];
    const float* b2        = (const float*)d_in[6];
    float* out = (float*)d_out;
    float* ws  = (float*)d_ws;

    cumsum_kernel<<<dim3(2 * HW / 256), dim3(256), 0, stream>>>(flows, ws + CUM_OFF);

    prep_kernel<<<dim3(HW / 256, LL), dim3(256), 0, stream>>>(images, w1, b1, ws);

    gsp_main<<<dim3(16 * 64), dim3(512), 0, stream>>>(ws, w2, b2, decay_log, out);
}

// Round 4
// 147.025 us; speedup vs baseline: 1.8410x; 1.0656x over previous
//
#include <hip/hip_runtime.h>

#define LL 16
#define CC 32
#define HIDN 16
#define HH 64
#define WW 64
#define HW 4096  // 64*64
#define NCHUNK 72   // total (t, k-chunk-of-2) pairs

// ws layout (floats):
#define CUM_OFF  0                                  // 131072
#define U_OFF    (LL * 2 * HW)                      // 1048576
#define V_OFF    (U_OFF + LL * HW * HIDN)           // 1048576
#define IMGT_OFF (V_OFF + LL * HW * HIDN)           // 2097152
#define A_OFF    (IMGT_OFF + LL * HW * CC)          // 72*CC*HW = 9437184
// total = 13,762,560 floats  (~52.5 MB)

// chunk tables: chunks of 2 k's per t; nch(t)=ceil((t+1)/2)
__device__ const int T_OF[NCHUNK] = {
    0, 1, 2,2, 3,3, 4,4,4, 5,5,5, 6,6,6,6, 7,7,7,7,
    8,8,8,8,8, 9,9,9,9,9, 10,10,10,10,10,10, 11,11,11,11,11,11,
    12,12,12,12,12,12,12, 13,13,13,13,13,13,13,
    14,14,14,14,14,14,14,14, 15,15,15,15,15,15,15,15 };
__device__ const int KC_OF[NCHUNK] = {
    0, 0, 0,1, 0,1, 0,1,2, 0,1,2, 0,1,2,3, 0,1,2,3,
    0,1,2,3,4, 0,1,2,3,4, 0,1,2,3,4,5, 0,1,2,3,4,5,
    0,1,2,3,4,5,6, 0,1,2,3,4,5,6,
    0,1,2,3,4,5,6,7, 0,1,2,3,4,5,6,7 };
__device__ const int CBASE[LL] = {0,1,2,4,6,9,12,16,20,25,30,36,42,49,56,64};
__device__ const int NCH[LL]   = {1,1,2,2,3,3,4,4,5,5,6,6,7,7,8,8};

// ---------------- cumsum of flows over L ----------------
__global__ __launch_bounds__(256) void cumsum_kernel(const float* __restrict__ flows,
                                                     float* __restrict__ cum) {
    int idx = blockIdx.x * 256 + threadIdx.x;   // p*HW + pix
    float acc = 0.0f;
#pragma unroll
    for (int l = 0; l < LL; ++l) {
        acc += flows[l * 2 * HW + idx];
        cum[l * 2 * HW + idx] = acc;
    }
}

// ---------------- prep: U/V halves (channel-last) + channel-last image copy ----
__global__ __launch_bounds__(256) void prep_kernel(const float* __restrict__ images,
                                                   const float* __restrict__ w1,
                                                   const float* __restrict__ b1,
                                                   float* __restrict__ ws) {
    __shared__ float w1s[HIDN * 2 * CC];  // 1024 floats
    const int tid = threadIdx.x;
    ((float4*)w1s)[tid] = ((const float4*)w1)[tid];
    __syncthreads();

    const int l  = blockIdx.y;
    const int px = blockIdx.x * 256 + tid;
    const float* img = images + (size_t)l * CC * HW;

    float x[CC];
#pragma unroll
    for (int c = 0; c < CC; ++c) x[c] = img[c * HW + px];

    float u[HIDN], v[HIDN];
#pragma unroll
    for (int o = 0; o < HIDN; ++o) { u[o] = 0.0f; v[o] = b1[o]; }
#pragma unroll
    for (int c = 0; c < CC; ++c) {
#pragma unroll
        for (int o = 0; o < HIDN; ++o) {
            u[o] = fmaf(w1s[o * 64 + c],      x[c], u[o]);
            v[o] = fmaf(w1s[o * 64 + CC + c], x[c], v[o]);
        }
    }

    float* Up = ws + U_OFF    + ((size_t)l * HW + px) * HIDN;
    float* Vp = ws + V_OFF    + ((size_t)l * HW + px) * HIDN;
    float* Tp = ws + IMGT_OFF + ((size_t)l * HW + px) * CC;
#pragma unroll
    for (int q = 0; q < 4; ++q) ((float4*)Up)[q] = ((float4*)u)[q];
#pragma unroll
    for (int q = 0; q < 4; ++q) ((float4*)Vp)[q] = ((float4*)v)[q];
#pragma unroll
    for (int q = 0; q < 8; ++q) ((float4*)Tp)[q] = ((float4*)x)[q];
}

// ---------------- phase A: balanced sample over (t, k-chunk) ----------------
// grid: (16 px-tiles, 72 chunks), block 256 threads = 256 px, all 32 channels
__global__ __launch_bounds__(256) void sample_kernel(const float* __restrict__ ws_in,
                                                     float* __restrict__ ws_out,
                                                     const float* __restrict__ w2,
                                                     const float* __restrict__ b2,
                                                     const float* __restrict__ decay_log) {
    __shared__ float w2s[2 * HIDN];
    __shared__ float b2s2[2];
    const int tid = threadIdx.x;
    if (tid < 2 * HIDN) w2s[tid] = w2[tid];
    if (tid < 2)        b2s2[tid] = b2[tid];
    __syncthreads();

    const int cid  = blockIdx.y;
    const int t    = T_OF[cid];
    const int k0   = KC_OF[cid] * 2;
    const int px   = blockIdx.x * 256 + tid;
    const int lpx  = px & 63;          // x coord
    const int row  = px >> 6;          // y coord

    const float* cum = ws_in + CUM_OFF;
    const float* Ub  = ws_in + U_OFF;
    const float* Vb  = ws_in + V_OFF;
    const float* imT = ws_in + IMGT_OFF;

    float ut[HIDN];
    {
        const float4* up = (const float4*)(Ub + ((size_t)t * HW + px) * HIDN);
#pragma unroll
        for (int q = 0; q < 4; ++q) ((float4*)ut)[q] = up[q];
    }

    const float cumtx = cum[(t * 2)     * HW + px];
    const float cumty = cum[(t * 2 + 1) * HW + px];
    const float lam   = expf(decay_log[0]);
    const float bgx   = (float)(2 * lpx + 1) * (1.0f / 64.0f) - 1.0f;
    const float bgy   = (float)(2 * row + 1) * (1.0f / 64.0f) - 1.0f;

    float acc[CC];
#pragma unroll
    for (int j = 0; j < CC; ++j) acc[j] = 0.0f;

#pragma unroll
    for (int dk = 0; dk < 2; ++dk) {
        const int k = k0 + dk;
        if (k > t) continue;   // uniform across block

        // tiny MLP: res = W2 * relu(U[t] + V[k]) + b2
        float res0 = b2s2[0], res1 = b2s2[1];
        {
            const float4* vp = (const float4*)(Vb + ((size_t)k * HW + px) * HIDN);
#pragma unroll
            for (int q = 0; q < 4; ++q) {
                float4 vq = vp[q];
                float h0 = fmaxf(ut[q * 4 + 0] + vq.x, 0.0f);
                float h1 = fmaxf(ut[q * 4 + 1] + vq.y, 0.0f);
                float h2 = fmaxf(ut[q * 4 + 2] + vq.z, 0.0f);
                float h3 = fmaxf(ut[q * 4 + 3] + vq.w, 0.0f);
                res0 = fmaf(w2s[q * 4 + 0], h0, res0);
                res0 = fmaf(w2s[q * 4 + 1], h1, res0);
                res0 = fmaf(w2s[q * 4 + 2], h2, res0);
                res0 = fmaf(w2s[q * 4 + 3], h3, res0);
                res1 = fmaf(w2s[HIDN + q * 4 + 0], h0, res1);
                res1 = fmaf(w2s[HIDN + q * 4 + 1], h1, res1);
                res1 = fmaf(w2s[HIDN + q * 4 + 2], h2, res1);
                res1 = fmaf(w2s[HIDN + q * 4 + 3], h3, res1);
            }
        }

        float gx = bgx + cumtx - cum[(k * 2)     * HW + px] + res0;
        float gy = bgy + cumty - cum[(k * 2 + 1) * HW + px] + res1;

        // wrap x: mod(gx+1, 2) - 1  (floor-mod)
        float xp = gx + 1.0f;
        xp = xp - floorf(xp * 0.5f) * 2.0f;
        float gxw = xp - 1.0f;

        float ix = ((gxw + 1.0f) * 64.0f - 1.0f) * 0.5f;
        float iy = ((gy  + 1.0f) * 64.0f - 1.0f) * 0.5f;

        float ix0f = floorf(ix), iy0f = floorf(iy);
        float fx1 = ix - ix0f, fy1 = iy - iy0f;
        float fx0 = 1.0f - fx1, fy0 = 1.0f - fy1;
        int ix0 = (int)ix0f, iy0 = (int)iy0f;
        int ix1 = ix0 + 1,   iy1 = iy0 + 1;

        const float wt = expf(-lam * (float)(t - k));

        int   off[4];
        float cwt[4];
        {
            int xi[4] = {ix0, ix1, ix0, ix1};
            int yi[4] = {iy0, iy0, iy1, iy1};
            float wwv[4] = {fx0 * fy0, fx1 * fy0, fx0 * fy1, fx1 * fy1};
#pragma unroll
            for (int j = 0; j < 4; ++j) {
                bool valid = (xi[j] >= 0) & (xi[j] < WW) & (yi[j] >= 0) & (yi[j] < HH);
                int xc = min(max(xi[j], 0), WW - 1);
                int yc = min(max(yi[j], 0), HH - 1);
                off[j] = yc * WW + xc;
                cwt[j] = valid ? wwv[j] * wt : 0.0f;
            }
        }

        const float* kbase = imT + (size_t)k * HW * CC;
#pragma unroll
        for (int j = 0; j < 4; ++j) {
            const float wj = cwt[j];
            const float4* cp = (const float4*)(kbase + (size_t)off[j] * CC);
#pragma unroll
            for (int q = 0; q < 8; ++q) {
                float4 p = cp[q];
                acc[q * 4 + 0] = fmaf(wj, p.x, acc[q * 4 + 0]);
                acc[q * 4 + 1] = fmaf(wj, p.y, acc[q * 4 + 1]);
                acc[q * 4 + 2] = fmaf(wj, p.z, acc[q * 4 + 2]);
                acc[q * 4 + 3] = fmaf(wj, p.w, acc[q * 4 + 3]);
            }
        }
    }

    // store partial slice: A[cid][c][px]  (coalesced scalar stores)
    float* Ap = ws_out + A_OFF + (size_t)cid * CC * HW + px;
#pragma unroll
    for (int c = 0; c < CC; ++c) Ap[c * HW] = acc[c];
}

// ---------------- phase B: reduce over k-chunks (pure streaming) ----------------
// 2048 blocks x 256 threads; one float4 of output per thread
__global__ __launch_bounds__(256) void reduce_kernel(const float* __restrict__ ws,
                                                     float* __restrict__ out) {
    const int gid = blockIdx.x * 256 + threadIdx.x;  // 0..524287
    const int t   = gid >> 15;                        // 32*1024 float4 per t
    const int c   = (gid >> 10) & 31;
    const int px4 = gid & 1023;

    const float4* A4 = (const float4*)(ws + A_OFF);
    const int base = CBASE[t];
    const int n    = NCH[t];

    float4 s = make_float4(0.0f, 0.0f, 0.0f, 0.0f);
    for (int kc = 0; kc < n; ++kc) {
        float4 a = A4[((size_t)(base + kc) * CC + c) * (HW / 4) + px4];
        s.x += a.x; s.y += a.y; s.z += a.z; s.w += a.w;
    }
    ((float4*)out)[gid] = s;
}

extern "C" void kernel_launch(void* const* d_in, const int* in_sizes, int n_in,
                              void* d_out, int out_size, void* d_ws, size_t ws_size,
                              hipStream_t stream) {
    const float* flows     = (const float*)d_in[0];
    const float* images    = (const float*)d_in[1];
    const float* decay_log = (const float*)d_in[2];
    const float* w1        = (const float*)d_in[3];
    const float* b1        = (const float*)d_in[4];
    const float* w2        = (const float*)d_in[5];
    const float* b2        = (const float*)d_in[6];
    float* out = (float*)d_out;
    float* ws  = (float*)d_ws;

    cumsum_kernel<<<dim3(2 * HW / 256), dim3(256), 0, stream>>>(flows, ws + CUM_OFF);

    prep_kernel<<<dim3(HW / 256, LL), dim3(256), 0, stream>>>(images, w1, b1, ws);

    sample_kernel<<<dim3(HW / 256, NCHUNK), dim3(256), 0, stream>>>(
        ws, ws, w2, b2, decay_log);

    reduce_kernel<<<dim3(2048), dim3(256), 0, stream>>>(ws, out);
}